// Round 5
// baseline (510.369 us; speedup 1.0000x reference)
//
#include <hip/hip_runtime.h>
#include <hip/hip_bf16.h>

// Problem constants (fixed by setup_inputs)
#define E_    8
#define DIN   2048
#define DOUT  2048
#define N_TOK 4096
#define NK    8192
#define R_    16
#define KEXT  2112            // 2048 + 16 (LoRA rank tail) + 48 zero pad, %64==0
#define KT_N  (KEXT / 64)     // 33 K-tiles
#define XROW_PAD 2052         // LDS row stride (shorts); 1026 words -> bank stride 2, conflict-free-ish

typedef __bf16 bf16x8 __attribute__((ext_vector_type(8)));
typedef float  f32x4  __attribute__((ext_vector_type(4)));
typedef unsigned short u16x8 __attribute__((ext_vector_type(8)));

static __device__ __forceinline__ void gld16(const void* g, void* l) {
  __builtin_amdgcn_global_load_lds(
      (const __attribute__((address_space(1))) unsigned int*)g,
      (__attribute__((address_space(3))) unsigned int*)l, 16, 0, 0);
}

static __device__ __forceinline__ unsigned short f2bfu(float f) {
  union { float f; unsigned int u; } v; v.f = f;
  unsigned int r = v.u + 0x7fffu + ((v.u >> 16) & 1u);  // round-to-nearest-even
  return (unsigned short)(r >> 16);
}

// ---- build Wbe[e][n][KEXT]: bf16(W) | bf16(loraB) | zeros. 4 rows per 256-thr block ----
__global__ void __launch_bounds__(256)
k_wconv(const float* __restrict__ w, const float* __restrict__ lb,
        unsigned short* __restrict__ wbe) {
  const long long row = (long long)blockIdx.x * 4 + (threadIdx.x >> 6);  // 0..16383
  const int lane = threadIdx.x & 63;
  const float4* src  = (const float4*)(w + row * DIN);
  const float4* lsrc = (const float4*)(lb + row * R_);
  ushort4* dst = (ushort4*)(wbe + row * KEXT);
  for (int u = lane; u < KEXT / 4; u += 64) {
    float4 v;
    if (u < 512)       v = src[u];
    else if (u < 516)  v = lsrc[u - 512];
    else               v = make_float4(0.f, 0.f, 0.f, 0.f);
    ushort4 o;
    o.x = f2bfu(v.x); o.y = f2bfu(v.y); o.z = f2bfu(v.z); o.w = f2bfu(v.w);
    dst[u] = o;
  }
}

// ---- lora_A fp32 -> bf16 ----
__global__ void k_aconv(const float* __restrict__ a, unsigned short* __restrict__ ab) {
  long long i = (long long)blockIdx.x * blockDim.x + threadIdx.x;   // n4 = 65536
  float4 v = ((const float4*)a)[i];
  ushort4 o;
  o.x = f2bfu(v.x); o.y = f2bfu(v.y); o.z = f2bfu(v.z); o.w = f2bfu(v.w);
  ((ushort4*)ab)[i] = o;
}

// ---- fused gather + XA: one wave per 16-slot expert-aligned tile ----
// Stage 16 gathered rows (fp32->bf16) through LDS; write Xe rows + zero pad +
// gate/tok; then rank-16 LoRA dot via MFMA off LDS; write XA tail into Xe.
__global__ void __launch_bounds__(64)
k_prep_x(const float* __restrict__ x, const unsigned short* __restrict__ Ab,
         const int* __restrict__ ssi, const float* __restrict__ gates,
         const int* __restrict__ kptr, const int* __restrict__ eoff,
         unsigned short* __restrict__ Xe, float* __restrict__ gate,
         int* __restrict__ tok) {
  __shared__ alignas(16) unsigned short lx[16 * XROW_PAD];  // 65,664 B

  int tile = blockIdx.x;
  int off_prev = 0, e = -1, m_start = 0, m_end = 0, acc_t = 0;
#pragma unroll
  for (int i = 0; i < E_; i++) {
    int oe = eoff[i];
    int te = (oe - off_prev + 15) >> 4;
    if (e < 0 && tile < acc_t + te) {
      e = i; m_start = off_prev + (tile - acc_t) * 16; m_end = oe;
    }
    acc_t += te; off_prev = oe;
  }
  if (e < 0) return;

  const int lane = threadIdx.x;
  const int kk = kptr[0];
  const int l15 = lane & 15, quad = lane >> 4;

  for (int r = 0; r < 16; r++) {
    int slot = m_start + r;
    bool valid = slot < m_end;
    int src_slot = valid ? slot : (m_end - 1);   // duplicate last row for clamped lanes
    int ssv = ssi[src_slot];
    int t = ssv / kk, sl = ssv - t * kk;
    const float4* srow = (const float4*)(x + (long long)t * DIN);
    ushort4* drow = (ushort4*)(Xe + (long long)slot * KEXT);
#pragma unroll
    for (int i2 = 0; i2 < 8; i2++) {
      int u = lane + i2 * 64;                    // float4 index 0..511
      float4 v = srow[u];
      ushort4 o;
      o.x = f2bfu(v.x); o.y = f2bfu(v.y); o.z = f2bfu(v.z); o.w = f2bfu(v.w);
      *(ushort4*)&lx[r * XROW_PAD + u * 4] = o;
      if (valid) drow[u] = o;
    }
    if (valid) {
      if (lane == 0) { gate[slot] = gates[t * kk + sl]; tok[slot] = t; }
      if (lane < 12) { ushort4 z; z.x = z.y = z.z = z.w = 0; drow[516 + lane] = z; }
    }
  }
  __syncthreads();

  // MFMA: A-frag = x rows from LDS, B-frag = Ab rows (bf16) from global.
  const unsigned short* bp = Ab + ((long long)e * R_ + l15) * DIN + quad * 8;
  f32x4 acc = (f32x4){0.f, 0.f, 0.f, 0.f};
#pragma unroll 4
  for (int k0 = 0; k0 < DIN; k0 += 32) {
    bf16x8 a = *(const bf16x8*)&lx[l15 * XROW_PAD + k0 + quad * 8];
    bf16x8 b = *(const bf16x8*)(bp + k0);
    acc = __builtin_amdgcn_mfma_f32_16x16x32_bf16(a, b, acc, 0, 0, 0);
  }
#pragma unroll
  for (int t = 0; t < 4; t++) {
    int slot = m_start + quad * 4 + t;
    if (slot < m_end)
      Xe[(long long)slot * KEXT + 2048 + l15] = f2bfu(2.0f * acc[t]);
  }
}

// ---- grouped GEMM over extended K (LoRA folded) + gated atomic scatter ----
// (unchanged from R4 for attribution)
__global__ void __launch_bounds__(256)
k_gemm(const unsigned short* __restrict__ Xe, const unsigned short* __restrict__ Wbe,
       const float* __restrict__ gate, const int* __restrict__ tok,
       const int* __restrict__ eoff, float* __restrict__ out) {
  __shared__ alignas(16) unsigned short sAB[2 * 128 * 64];  // A tile | B tile, 32 KB
  __shared__ float gs[128];
  __shared__ int   ts[128];

  const int id = blockIdx.x;          // 1152 blocks
  const int xcd = id & 7, local = id >> 3;   // local 0..143
  const int mt = local % 72;
  const int nt = (xcd << 1) | (local / 72);  // 0..15
  const int n_start = nt << 7;

  int off_prev = 0, e = -1, m_start = 0, m_end = 0, acc_t = 0;
#pragma unroll
  for (int i = 0; i < E_; i++) {
    int oe = eoff[i];
    int te = (oe - off_prev + 127) >> 7;
    if (e < 0 && mt < acc_t + te) {
      e = i; m_start = off_prev + (mt - acc_t) * 128; m_end = oe;
    }
    acc_t += te;
    off_prev = oe;
  }
  if (e < 0) return;

  const int tid = threadIdx.x;
  const int w = tid >> 6, lane = tid & 63;
  const int wm = w & 1, wn = w >> 1;
  const int quad = lane >> 4, l15 = lane & 15;

  if (tid < 128) {
    int gm = m_start + tid; if (gm >= m_end) gm = m_end - 1;
    gs[tid] = gate[gm];
    ts[tid] = tok[gm];
  }

  f32x4 acc[4][4];
#pragma unroll
  for (int mi = 0; mi < 4; mi++)
#pragma unroll
    for (int ni = 0; ni < 4; ni++)
      acc[mi][ni] = (f32x4){0.f, 0.f, 0.f, 0.f};

  const int srow = lane >> 3;                // row within 8-row staging chunk
  const int scol = ((lane & 7) ^ srow) * 8;  // SWIZZLED source bf16 col within BK=64
  const unsigned short* Wbase = Wbe + (long long)e * DOUT * KEXT;

  for (int kt = 0; kt < KT_N; kt++) {
    const int k0 = kt * 64;
#pragma unroll
    for (int j = 0; j < 4; j++) {
      int c = w * 4 + j;              // chunk 0..15 (8 rows x 64 cols each)
      int rt = c * 8 + srow;
      int ga = m_start + rt; if (ga >= m_end) ga = m_end - 1;
      gld16(Xe + (long long)ga * KEXT + k0 + scol, &sAB[c * 512 + lane * 8]);
      gld16(Wbase + (long long)(n_start + rt) * KEXT + k0 + scol,
            &sAB[8192 + c * 512 + lane * 8]);
    }
    __syncthreads();
#pragma unroll
    for (int ks = 0; ks < 2; ks++) {
      const int kx = (((ks << 2) | quad) ^ (l15 & 7)) << 3;
      bf16x8 af[4], bfr[4];
#pragma unroll
      for (int mi = 0; mi < 4; mi++)
        af[mi] = *(const bf16x8*)&sAB[(wm * 64 + mi * 16 + l15) * 64 + kx];
#pragma unroll
      for (int ni = 0; ni < 4; ni++)
        bfr[ni] = *(const bf16x8*)&sAB[8192 + (wn * 64 + ni * 16 + l15) * 64 + kx];
#pragma unroll
      for (int mi = 0; mi < 4; mi++)
#pragma unroll
        for (int ni = 0; ni < 4; ni++)
          acc[mi][ni] = __builtin_amdgcn_mfma_f32_16x16x32_bf16(
              af[mi], bfr[ni], acc[mi][ni], 0, 0, 0);
    }
    __syncthreads();
  }

#pragma unroll
  for (int ni = 0; ni < 4; ni++) {
    int n = n_start + wn * 64 + ni * 16 + l15;
#pragma unroll
    for (int mi = 0; mi < 4; mi++) {
#pragma unroll
      for (int t4 = 0; t4 < 4; t4++) {
        int row = wm * 64 + mi * 16 + quad * 4 + t4;
        if (m_start + row >= m_end) continue;
        float o = acc[mi][ni][t4] * gs[row];
        atomicAdd(out + (long long)ts[row] * DOUT + n, o);  // exactly k=2 adds/elem
      }
    }
  }
}

extern "C" void kernel_launch(void* const* d_in, const int* in_sizes, int n_in,
                              void* d_out, int out_size, void* d_ws, size_t ws_size,
                              hipStream_t stream) {
  (void)in_sizes; (void)n_in; (void)out_size; (void)ws_size;
  const float* inputs = (const float*)d_in[0];
  const float* weight = (const float*)d_in[1];
  const float* lora_A = (const float*)d_in[2];
  const float* lora_B = (const float*)d_in[3];
  const float* gates  = (const float*)d_in[4];
  const int* sei  = (const int*)d_in[5];
  const int* ssi  = (const int*)d_in[6];
  const int* eoff = (const int*)d_in[7];
  const int* kptr = (const int*)d_in[8];
  (void)sei;
  float* out = (float*)d_out;

  // workspace layout (~104.4 MB)
  unsigned char* ws = (unsigned char*)d_ws;
  unsigned short* Wbe = (unsigned short*)ws;                 // 8*2048*2112*2 = 69,206,016 B
  unsigned short* Xe  = (unsigned short*)(ws + 69206016);    // 8192*2112*2   = 34,603,008 B
  unsigned short* Ab  = (unsigned short*)(ws + 103809024);   // 8*16*2048*2   =    524,288 B
  float* gate = (float*)(ws + 104333312);                    // 8192*4
  int*   tok  = (int*)(ws + 104366080);                      // 8192*4

  hipMemsetAsync(d_out, 0, (size_t)N_TOK * DOUT * sizeof(float), stream);
  k_wconv<<<E_ * DOUT / 4, 256, 0, stream>>>(weight, lora_B, Wbe);
  k_aconv<<<256, 256, 0, stream>>>(lora_A, Ab);
  k_prep_x<<<520, 64, 0, stream>>>(inputs, Ab, ssi, gates, kptr, eoff, Xe, gate, tok);
  k_gemm<<<1152, 256, 0, stream>>>(Xe, Wbe, gate, tok, eoff, out);
}